// Round 1
// baseline (1955.342 us; speedup 1.0000x reference)
//
#include <hip/hip_runtime.h>
#include <hip/hip_bf16.h>
#include <stdint.h>

// Problem constants (from reference setup_inputs)
#define NB      256     // batch (graphs)
#define NN      100     // nodes per graph
#define NE      1600    // edges per graph (before self loops)
#define NEL     1700    // edges + self loops
#define FIN     2048    // input features
#define HG      512     // GCN hidden
#define DG      256     // GAT out
#define PO      1024    // proj out
#define KTOP    50
#define NEG_SLOPE 0.2f

// ---------------------------------------------------------------------------
// fp32 GEMM, row-major A[M,K] * B[K,N] -> C[M,N].  BM=BN=128, BK=16,
// 256 threads, 8x8 micro-tile per thread. M%128==0, N%128==0, K%16==0.
// ---------------------------------------------------------------------------
__global__ __launch_bounds__(256) void gemm_f32_nn(
    const float* __restrict__ A, const float* __restrict__ Bm,
    float* __restrict__ C, int M, int N, int K) {
  __shared__ float As[16][128];   // transposed A tile: As[k][m]
  __shared__ float Bs[16][128];   // Bs[k][n]
  const int tid = threadIdx.x;
  const int bn0 = blockIdx.x * 128;
  const int bm0 = blockIdx.y * 128;
  const int tx = tid & 15, ty = tid >> 4;
  const int row0 = ty * 8, col0 = tx * 8;
  float acc[8][8] = {};

  for (int k0 = 0; k0 < K; k0 += 16) {
    __syncthreads();
#pragma unroll
    for (int u = 0; u < 2; u++) {
      int c = tid + u * 256;
      // A: 128 rows x 16 cols = 512 float4 chunks
      int ar = c >> 2, akc = (c & 3) * 4;
      float4 av = *(const float4*)&A[(size_t)(bm0 + ar) * K + k0 + akc];
      As[akc + 0][ar] = av.x; As[akc + 1][ar] = av.y;
      As[akc + 2][ar] = av.z; As[akc + 3][ar] = av.w;
      // B: 16 rows x 128 cols
      int br = c >> 5, bc = (c & 31) * 4;
      *(float4*)&Bs[br][bc] =
          *(const float4*)&Bm[(size_t)(k0 + br) * N + bn0 + bc];
    }
    __syncthreads();
#pragma unroll
    for (int kk = 0; kk < 16; kk++) {
      float4 a0 = *(const float4*)&As[kk][row0];
      float4 a1 = *(const float4*)&As[kk][row0 + 4];
      float4 b0 = *(const float4*)&Bs[kk][col0];
      float4 b1 = *(const float4*)&Bs[kk][col0 + 4];
      float a[8] = {a0.x, a0.y, a0.z, a0.w, a1.x, a1.y, a1.z, a1.w};
      float b[8] = {b0.x, b0.y, b0.z, b0.w, b1.x, b1.y, b1.z, b1.w};
#pragma unroll
      for (int i = 0; i < 8; i++)
#pragma unroll
        for (int j = 0; j < 8; j++)
          acc[i][j] = fmaf(a[i], b[j], acc[i][j]);
    }
  }
#pragma unroll
  for (int i = 0; i < 8; i++) {
    float4 o0 = {acc[i][0], acc[i][1], acc[i][2], acc[i][3]};
    float4 o1 = {acc[i][4], acc[i][5], acc[i][6], acc[i][7]};
    size_t base = (size_t)(bm0 + row0 + i) * N + bn0 + col0;
    *(float4*)&C[base] = o0;
    *(float4*)&C[base + 4] = o1;
  }
}

// ---------------------------------------------------------------------------
// GCN aggregation: per-graph block. h1 = relu(Dinv(A+I)Dinv * h0 + b)
// 512 threads (= HG), CSR buckets in LDS, gather h0 from L2.
// ---------------------------------------------------------------------------
__global__ __launch_bounds__(512) void gcn_agg(
    const float* __restrict__ h0, const int* __restrict__ ei,
    const float* __restrict__ b_gcn, float* __restrict__ h1) {
  const int g = blockIdx.x;
  const int tid = threadIdx.x;
  __shared__ int   deg[NN];
  __shared__ float sdinv[NN];
  __shared__ int   offs[NN + 1];
  __shared__ int   fill[NN];
  __shared__ int   eSrc[NEL];
  __shared__ float eNrm[NEL];
  const int* src = ei + (size_t)g * 2 * NE;
  const int* dst = src + NE;

  if (tid < NN) deg[tid] = 1;          // self loop
  __syncthreads();
  for (int e = tid; e < NE; e += 512) atomicAdd(&deg[dst[e]], 1);
  __syncthreads();
  if (tid < NN) sdinv[tid] = rsqrtf(fmaxf((float)deg[tid], 1e-12f));
  if (tid == 0) {
    int s = 0;
    for (int n = 0; n < NN; n++) { offs[n] = s; s += deg[n]; }
    offs[NN] = s;
  }
  __syncthreads();
  if (tid < NN) fill[tid] = offs[tid];
  __syncthreads();
  for (int e = tid; e < NE; e += 512) {
    int s = src[e], d = dst[e];
    int p = atomicAdd(&fill[d], 1);
    eSrc[p] = s;
    eNrm[p] = sdinv[s] * sdinv[d];
  }
  if (tid < NN) {   // self loop entry
    int p = atomicAdd(&fill[tid], 1);
    eSrc[p] = tid;
    eNrm[p] = sdinv[tid] * sdinv[tid];
  }
  __syncthreads();

  const float* h0g = h0 + (size_t)g * NN * HG;
  float* h1g = h1 + (size_t)g * NN * HG;
  const float bias = b_gcn[tid];       // blockDim == HG
  for (int n = 0; n < NN; n++) {
    float acc = bias;
    const int p1 = offs[n + 1];
    for (int p = offs[n]; p < p1; p++)
      acc = fmaf(h0g[(size_t)eSrc[p] * HG + tid], eNrm[p], acc);
    h1g[(size_t)n * HG + tid] = fmaxf(acc, 0.f);
  }
}

// float -> order-preserving unsigned (for max / sort keys)
__device__ inline unsigned fmap(float f) {
  unsigned b = __float_as_uint(f);
  return (b & 0x80000000u) ? ~b : (b | 0x80000000u);
}
__device__ inline float funmap(unsigned u) {
  return __uint_as_float((u & 0x80000000u) ? (u & 0x7fffffffu) : ~u);
}

// ---------------------------------------------------------------------------
// GAT: per-graph block, 256 threads (= DG).
// h2 = GAT hidden (from GEMM2).  Computes attention (segment softmax by dst),
// gnn_out = sum(alpha * h2[src]) + b_gat, and patch scores.
// ---------------------------------------------------------------------------
__global__ __launch_bounds__(256) void gat_kernel(
    const float* __restrict__ h2, const int* __restrict__ ei,
    const float* __restrict__ a_src, const float* __restrict__ a_dst,
    const float* __restrict__ b_gat, float* __restrict__ out,
    float* __restrict__ scores) {
  const int g = blockIdx.x, tid = threadIdx.x;
  __shared__ float    sAs[NN], sAd[NN];
  __shared__ unsigned mKey[NN];
  __shared__ float    sSum[NN], sAtt[NN];
  __shared__ int      sCnt[NN], degl[NN];
  __shared__ int      offs[NN + 1], fill[NN];
  __shared__ float    eV[NEL];
  __shared__ int      eS[NEL];
  __shared__ float    eA[NEL];
  const int* src = ei + (size_t)g * 2 * NE;
  const int* dst = src + NE;
  const float* h2g = h2 + (size_t)g * NN * DG;

  // phase 1: asrc/adst per node (wave per node, 4 waves round-robin)
  const int lane = tid & 63, wv = tid >> 6;
  for (int n = wv; n < NN; n += 4) {
    float4 hv  = *(const float4*)&h2g[(size_t)n * DG + lane * 4];
    float4 as4 = *(const float4*)&a_src[lane * 4];
    float4 ad4 = *(const float4*)&a_dst[lane * 4];
    float ps = hv.x * as4.x + hv.y * as4.y + hv.z * as4.z + hv.w * as4.w;
    float pd = hv.x * ad4.x + hv.y * ad4.y + hv.z * ad4.z + hv.w * ad4.w;
#pragma unroll
    for (int o = 32; o; o >>= 1) {
      ps += __shfl_down(ps, o);
      pd += __shfl_down(pd, o);
    }
    if (lane == 0) { sAs[n] = ps; sAd[n] = pd; }
  }
  if (tid < NN) {
    mKey[tid] = 0u; sSum[tid] = 0.f; sAtt[tid] = 0.f;
    sCnt[tid] = 0;  degl[tid] = 1;
  }
  __syncthreads();

  // phase 2: e = leaky_relu(asrc[s]+adst[d]); segment max; bucket sizes
  for (int i = tid; i < NEL; i += 256) {
    int s, d;
    if (i < NE) { s = src[i]; d = dst[i]; } else { s = d = i - NE; }
    float e = sAs[s] + sAd[d];
    e = (e > 0.f) ? e : NEG_SLOPE * e;
    eV[i] = e;
    atomicMax(&mKey[d], fmap(e));
    if (i < NE) atomicAdd(&degl[d], 1);
  }
  __syncthreads();

  // phase 3: exp(e - m), segment sum
  for (int i = tid; i < NEL; i += 256) {
    int d = (i < NE) ? dst[i] : i - NE;
    float ex = expf(eV[i] - funmap(mKey[d]));
    eV[i] = ex;
    atomicAdd(&sSum[d], ex);
  }
  if (tid == 0) {
    int s = 0;
    for (int n = 0; n < NN; n++) { offs[n] = s; s += degl[n]; }
    offs[NN] = s;
  }
  __syncthreads();
  if (tid < NN) fill[tid] = offs[tid];
  __syncthreads();

  // phase 4: alpha, score accumulation, CSR fill (by dst)
  for (int i = tid; i < NEL; i += 256) {
    int s, d;
    if (i < NE) { s = src[i]; d = dst[i]; } else { s = d = i - NE; }
    float al = eV[i] / sSum[d];
    atomicAdd(&sAtt[s], al);
    atomicAdd(&sAtt[d], al);
    atomicAdd(&sCnt[s], 1);
    atomicAdd(&sCnt[d], 1);
    int p = atomicAdd(&fill[d], 1);
    eS[p] = s;
    eA[p] = al;
  }
  __syncthreads();

  if (tid < NN) scores[g * NN + tid] = sAtt[tid] / (float)sCnt[tid];

  // phase 5: out[d] = sum alpha * h2[src] + b_gat  (256 threads = DG)
  float* outg = out + (size_t)g * NN * DG;
  const float bias = b_gat[tid];
  for (int n = 0; n < NN; n++) {
    float acc = bias;
    const int p1 = offs[n + 1];
    for (int p = offs[n]; p < p1; p++)
      acc = fmaf(h2g[(size_t)eS[p] * DG + tid], eA[p], acc);
    outg[(size_t)n * DG + tid] = acc;
  }
}

// ---------------------------------------------------------------------------
// Top-50 of 25600 scores. Single block, 1024 threads, 25 keys/thread in regs.
// Key = (ordered_float << 32) | ~idx  -> descending sort order == score desc,
// tie-break lower index first (matches jax.lax.top_k).
// ---------------------------------------------------------------------------
__global__ __launch_bounds__(1024) void topk_kernel(
    const float* __restrict__ scores, int* __restrict__ topk) {
  const int tid = threadIdx.x;
  unsigned long long keys[25];
#pragma unroll
  for (int u = 0; u < 25; u++) {
    int idx = tid + u * 1024;
    unsigned mk = fmap(scores[idx]);
    keys[u] = ((unsigned long long)mk << 32) | (unsigned)(~idx);
  }
  __shared__ unsigned long long wmax[16];
  __shared__ unsigned long long chosen;
  for (int r = 0; r < KTOP; r++) {
    unsigned long long best = 0ull;
#pragma unroll
    for (int u = 0; u < 25; u++) best = (keys[u] > best) ? keys[u] : best;
#pragma unroll
    for (int o = 32; o; o >>= 1) {
      unsigned long long other = __shfl_down(best, o);
      best = (other > best) ? other : best;
    }
    if ((tid & 63) == 0) wmax[tid >> 6] = best;
    __syncthreads();
    if (tid == 0) {
      unsigned long long m = wmax[0];
      for (int w = 1; w < 16; w++) m = (wmax[w] > m) ? wmax[w] : m;
      chosen = m;
      topk[r] = (int)(~(unsigned)m);
    }
    __syncthreads();
    unsigned long long c = chosen;
#pragma unroll
    for (int u = 0; u < 25; u++)
      if (keys[u] == c) keys[u] = 0ull;
    __syncthreads();
  }
}

// ---------------------------------------------------------------------------
// Project only the 50 selected rows: out[i,:] = gnn[idx[i],:] @ W_proj + b.
// grid = 50*4 blocks, 256 threads; block handles one row x 256 cols.
// ---------------------------------------------------------------------------
__global__ __launch_bounds__(256) void proj_kernel(
    const float* __restrict__ gnn, const int* __restrict__ topk,
    const float* __restrict__ Wp, const float* __restrict__ bp,
    float* __restrict__ outp) {
  const int bi = blockIdx.x >> 2;
  const int c0 = (blockIdx.x & 3) * 256;
  const int tid = threadIdx.x;
  __shared__ float row[DG];
  const int node = topk[bi];
  row[tid] = gnn[(size_t)node * DG + tid];   // 256 threads == DG
  __syncthreads();
  float acc = 0.f;
  for (int k = 0; k < DG; k++)
    acc = fmaf(row[k], Wp[(size_t)k * PO + c0 + tid], acc);
  outp[(size_t)bi * PO + c0 + tid] = acc + bp[c0 + tid];
}

// ---------------------------------------------------------------------------
extern "C" void kernel_launch(void* const* d_in, const int* in_sizes, int n_in,
                              void* d_out, int out_size, void* d_ws,
                              size_t ws_size, hipStream_t stream) {
  const float* x      = (const float*)d_in[0];
  const int*   ei     = (const int*)d_in[1];
  const float* W_gcn  = (const float*)d_in[2];
  const float* b_gcn  = (const float*)d_in[3];
  const float* W_gat  = (const float*)d_in[4];
  const float* b_gat  = (const float*)d_in[5];
  const float* a_src  = (const float*)d_in[6];
  const float* a_dst  = (const float*)d_in[7];
  const float* W_proj = (const float*)d_in[8];
  const float* b_proj = (const float*)d_in[9];
  float* outp = (float*)d_out;

  // workspace layout (~105 MB):
  //   bufA: 25600*512 f32 (H0, later H2)   52,428,800 B
  //   bufB: 25600*512 f32 (H1, later gnn)  52,428,800 B
  //   scores: 25600 f32                       102,400 B
  //   topk:   50 int
  char* ws = (char*)d_ws;
  float* bufA   = (float*)ws;
  float* bufB   = (float*)(ws + 52428800);
  float* scores = (float*)(ws + 104857600);
  int*   topk   = (int*)(ws + 104960000);

  const int M = NB * NN;  // 25600

  // 1) H0 = x @ W_gcn            [25600,2048]x[2048,512]
  gemm_f32_nn<<<dim3(HG / 128, M / 128), 256, 0, stream>>>(
      x, W_gcn, bufA, M, HG, FIN);
  // 2) H1 = relu(norm-agg(H0) + b_gcn)
  gcn_agg<<<NB, 512, 0, stream>>>(bufA, ei, b_gcn, bufB);
  // 3) H2 = H1 @ W_gat           [25600,512]x[512,256]  (overwrites bufA)
  gemm_f32_nn<<<dim3(DG / 128, M / 128), 256, 0, stream>>>(
      bufB, W_gat, bufA, M, DG, HG);
  // 4) GAT attention + aggregation + patch scores (gnn_out -> bufB)
  gat_kernel<<<NB, 256, 0, stream>>>(bufA, ei, a_src, a_dst, b_gat, bufB,
                                     scores);
  // 5) top-50 selection
  topk_kernel<<<1, 1024, 0, stream>>>(scores, topk);
  // 6) project selected rows
  proj_kernel<<<KTOP * 4, 256, 0, stream>>>(bufB, topk, W_proj, b_proj, outp);
}

// Round 2
// 774.817 us; speedup vs baseline: 2.5236x; 2.5236x over previous
//
#include <hip/hip_runtime.h>
#include <hip/hip_bf16.h>
#include <stdint.h>

#define NB      256
#define NN      100
#define NE      1600
#define NEL     1700
#define FIN     2048
#define HG      512
#define DG      256
#define PO      1024
#define KTOP    50
#define NEG_SLOPE 0.2f

typedef __attribute__((ext_vector_type(8))) short bf16x8;
typedef __attribute__((ext_vector_type(4))) float f32x4;

// fp32 -> bf16 (RNE) bit helpers
__device__ inline ushort f2bf(float x) {
  unsigned u = __float_as_uint(x);
  return (ushort)((u + 0x7fffu + ((u >> 16) & 1u)) >> 16);
}
__device__ inline float bf2f(ushort b) {
  return __uint_as_float((unsigned)b << 16);
}

// ---------------------------------------------------------------------------
// Transpose + hi/lo split of weight W[K][N] -> hiT/loT [N][K] (bf16 bits)
// ---------------------------------------------------------------------------
template <int KSH>
__global__ void tsplit(const float* __restrict__ W, ushort* __restrict__ hiT,
                       ushort* __restrict__ loT, int N) {
  const int K = 1 << KSH;
  int e = blockIdx.x * 256 + threadIdx.x;
  if (e >= N * K) return;
  int n = e >> KSH, k = e & (K - 1);
  float v = W[(size_t)k * N + n];
  ushort h = f2bf(v);
  hiT[e] = h;
  loT[e] = f2bf(v - bf2f(h));
}

// ---------------------------------------------------------------------------
// Split-precision bf16 MFMA GEMM:  C = A(f32,[M][K]) * B(f32 as hi/lo,[N][K]^T)
// C fp32-accurate via 3 terms: Ahi*Bhi + Alo*Bhi + Ahi*Blo.
// BM=128, BN template (256 or 128), BK=32, 256 threads = 4 waves (2x2),
// wave tile 64 x BN/2, 16x16x32 bf16 MFMA. A split to hi/lo during staging.
// ---------------------------------------------------------------------------
template <int BN, int KSH>
__global__ __launch_bounds__(256, 2) void gemm_split_mfma(
    const float* __restrict__ A, const ushort* __restrict__ Bhi_t,
    const ushort* __restrict__ Blo_t, float* __restrict__ C, int M, int N) {
  constexpr int K = 1 << KSH;
  constexpr int FN = BN / 32;             // frags per wave along N
  __shared__ ushort Ahi[128 * 32], Alo[128 * 32];
  __shared__ ushort Bsh[BN * 32], Bsl[BN * 32];
  const int tid = threadIdx.x;
  const int lane = tid & 63;
  const int wid = tid >> 6;
  const int wm0 = (wid & 1) * 64;
  const int wn0 = (wid >> 1) * (BN / 2);
  const int bm0 = blockIdx.y * 128, bn0 = blockIdx.x * BN;
  const int r16 = lane & 15, g16 = lane >> 4;
  f32x4 acc[4][FN] = {};

  for (int k0 = 0; k0 < K; k0 += 32) {
    __syncthreads();
    // stage A tile (f32 -> hi/lo): 128 rows x 32 cols = 1024 chunks of 4 f32
#pragma unroll
    for (int u = 0; u < 4; u++) {
      int c = tid + u * 256;
      int row = c >> 3, kc = (c & 7) * 4;
      float4 v = *(const float4*)&A[((size_t)(bm0 + row) << KSH) + k0 + kc];
      ushort4 h, l;
      h.x = f2bf(v.x); l.x = f2bf(v.x - bf2f(h.x));
      h.y = f2bf(v.y); l.y = f2bf(v.y - bf2f(h.y));
      h.z = f2bf(v.z); l.z = f2bf(v.z - bf2f(h.z));
      h.w = f2bf(v.w); l.w = f2bf(v.w - bf2f(h.w));
      *(ushort4*)&Ahi[row * 32 + kc] = h;
      *(ushort4*)&Alo[row * 32 + kc] = l;
    }
    // stage B tile (already bf16 hi/lo, transposed): BN rows x 32, 16B chunks
#pragma unroll
    for (int u = 0; u < BN / 64; u++) {
      int c = tid + u * 256;
      int col = c >> 2, kc = (c & 3) * 8;
      size_t gofs = ((size_t)(bn0 + col) << KSH) + k0 + kc;
      *(uint4*)&Bsh[col * 32 + kc] = *(const uint4*)&Bhi_t[gofs];
      *(uint4*)&Bsl[col * 32 + kc] = *(const uint4*)&Blo_t[gofs];
    }
    __syncthreads();
    bf16x8 ah[4], al[4];
#pragma unroll
    for (int m = 0; m < 4; m++) {
      ah[m] = *(const bf16x8*)&Ahi[(wm0 + m * 16 + r16) * 32 + g16 * 8];
      al[m] = *(const bf16x8*)&Alo[(wm0 + m * 16 + r16) * 32 + g16 * 8];
    }
#pragma unroll
    for (int n = 0; n < FN; n++) {
      bf16x8 bh = *(const bf16x8*)&Bsh[(wn0 + n * 16 + r16) * 32 + g16 * 8];
      bf16x8 bl = *(const bf16x8*)&Bsl[(wn0 + n * 16 + r16) * 32 + g16 * 8];
#pragma unroll
      for (int m = 0; m < 4; m++) {
        acc[m][n] = __builtin_amdgcn_mfma_f32_16x16x32_bf16(ah[m], bh, acc[m][n], 0, 0, 0);
        acc[m][n] = __builtin_amdgcn_mfma_f32_16x16x32_bf16(al[m], bh, acc[m][n], 0, 0, 0);
        acc[m][n] = __builtin_amdgcn_mfma_f32_16x16x32_bf16(ah[m], bl, acc[m][n], 0, 0, 0);
      }
    }
  }
  const int crow = g16 * 4;
#pragma unroll
  for (int m = 0; m < 4; m++)
#pragma unroll
    for (int n = 0; n < FN; n++)
#pragma unroll
      for (int r = 0; r < 4; r++)
        C[(size_t)(bm0 + wm0 + m * 16 + crow + r) * N + bn0 + wn0 + n * 16 + r16] =
            acc[m][n][r];
}

// ---------------------------------------------------------------------------
// GCN aggregation: per-graph block, 512 threads. CSR in LDS, then 4 node
// groups x 128 threads, float4 over 512 features. h1 = relu(agg + b) (f32).
// ---------------------------------------------------------------------------
__global__ __launch_bounds__(512) void gcn_agg(
    const float* __restrict__ h0, const int* __restrict__ ei,
    const float* __restrict__ b_gcn, float* __restrict__ h1) {
  const int g = blockIdx.x, tid = threadIdx.x;
  __shared__ int   deg[NN];
  __shared__ float sdinv[NN];
  __shared__ int   offs[NN + 1], fill[NN];
  __shared__ int   eSrc[NEL];
  __shared__ float eNrm[NEL];
  const int* src = ei + (size_t)g * 2 * NE;
  const int* dst = src + NE;

  if (tid < NN) deg[tid] = 1;
  __syncthreads();
  for (int e = tid; e < NE; e += 512) atomicAdd(&deg[dst[e]], 1);
  __syncthreads();
  if (tid < NN) sdinv[tid] = rsqrtf(fmaxf((float)deg[tid], 1e-12f));
  if (tid == 0) {
    int s = 0;
    for (int n = 0; n < NN; n++) { offs[n] = s; s += deg[n]; }
    offs[NN] = s;
  }
  __syncthreads();
  if (tid < NN) fill[tid] = offs[tid];
  __syncthreads();
  for (int e = tid; e < NE; e += 512) {
    int s = src[e], d = dst[e];
    int p = atomicAdd(&fill[d], 1);
    eSrc[p] = s;
    eNrm[p] = sdinv[s] * sdinv[d];
  }
  if (tid < NN) {
    int p = atomicAdd(&fill[tid], 1);
    eSrc[p] = tid;
    eNrm[p] = sdinv[tid] * sdinv[tid];
  }
  __syncthreads();

  const float* h0g = h0 + (size_t)g * NN * HG;
  float* h1g = h1 + (size_t)g * NN * HG;
  const int grp = tid >> 7, tf = tid & 127;
  float4 bias = *(const float4*)&b_gcn[tf * 4];
  for (int n = grp; n < NN; n += 4) {
    float4 acc = bias;
    const int p1 = offs[n + 1];
    for (int p = offs[n]; p < p1; p++) {
      float nr = eNrm[p];
      float4 hv = *(const float4*)&h0g[(size_t)eSrc[p] * HG + tf * 4];
      acc.x = fmaf(hv.x, nr, acc.x);
      acc.y = fmaf(hv.y, nr, acc.y);
      acc.z = fmaf(hv.z, nr, acc.z);
      acc.w = fmaf(hv.w, nr, acc.w);
    }
    acc.x = fmaxf(acc.x, 0.f); acc.y = fmaxf(acc.y, 0.f);
    acc.z = fmaxf(acc.z, 0.f); acc.w = fmaxf(acc.w, 0.f);
    *(float4*)&h1g[(size_t)n * HG + tf * 4] = acc;
  }
}

__device__ inline unsigned fmap(float f) {
  unsigned b = __float_as_uint(f);
  return (b & 0x80000000u) ? ~b : (b | 0x80000000u);
}
__device__ inline float funmap(unsigned u) {
  return __uint_as_float((u & 0x80000000u) ? (u & 0x7fffffffu) : ~u);
}

// ---------------------------------------------------------------------------
// GAT: per-graph block, 256 threads.
// ---------------------------------------------------------------------------
__global__ __launch_bounds__(256) void gat_kernel(
    const float* __restrict__ h2, const int* __restrict__ ei,
    const float* __restrict__ a_src, const float* __restrict__ a_dst,
    const float* __restrict__ b_gat, float* __restrict__ out,
    float* __restrict__ scores) {
  const int g = blockIdx.x, tid = threadIdx.x;
  __shared__ float    sAs[NN], sAd[NN];
  __shared__ unsigned mKey[NN];
  __shared__ float    sSum[NN], sAtt[NN];
  __shared__ int      sCnt[NN], degl[NN];
  __shared__ int      offs[NN + 1], fill[NN];
  __shared__ float    eV[NEL];
  __shared__ int      eS[NEL];
  __shared__ float    eA[NEL];
  const int* src = ei + (size_t)g * 2 * NE;
  const int* dst = src + NE;
  const float* h2g = h2 + (size_t)g * NN * DG;

  const int lane = tid & 63, wv = tid >> 6;
  for (int n = wv; n < NN; n += 4) {
    float4 hv  = *(const float4*)&h2g[(size_t)n * DG + lane * 4];
    float4 as4 = *(const float4*)&a_src[lane * 4];
    float4 ad4 = *(const float4*)&a_dst[lane * 4];
    float ps = hv.x * as4.x + hv.y * as4.y + hv.z * as4.z + hv.w * as4.w;
    float pd = hv.x * ad4.x + hv.y * ad4.y + hv.z * ad4.z + hv.w * ad4.w;
#pragma unroll
    for (int o = 32; o; o >>= 1) {
      ps += __shfl_down(ps, o);
      pd += __shfl_down(pd, o);
    }
    if (lane == 0) { sAs[n] = ps; sAd[n] = pd; }
  }
  if (tid < NN) {
    mKey[tid] = 0u; sSum[tid] = 0.f; sAtt[tid] = 0.f;
    sCnt[tid] = 0;  degl[tid] = 1;
  }
  __syncthreads();

  for (int i = tid; i < NEL; i += 256) {
    int s, d;
    if (i < NE) { s = src[i]; d = dst[i]; } else { s = d = i - NE; }
    float e = sAs[s] + sAd[d];
    e = (e > 0.f) ? e : NEG_SLOPE * e;
    eV[i] = e;
    atomicMax(&mKey[d], fmap(e));
    if (i < NE) atomicAdd(&degl[d], 1);
  }
  __syncthreads();

  for (int i = tid; i < NEL; i += 256) {
    int d = (i < NE) ? dst[i] : i - NE;
    float ex = expf(eV[i] - funmap(mKey[d]));
    eV[i] = ex;
    atomicAdd(&sSum[d], ex);
  }
  if (tid == 0) {
    int s = 0;
    for (int n = 0; n < NN; n++) { offs[n] = s; s += degl[n]; }
    offs[NN] = s;
  }
  __syncthreads();
  if (tid < NN) fill[tid] = offs[tid];
  __syncthreads();

  for (int i = tid; i < NEL; i += 256) {
    int s, d;
    if (i < NE) { s = src[i]; d = dst[i]; } else { s = d = i - NE; }
    float al = eV[i] / sSum[d];
    atomicAdd(&sAtt[s], al);
    atomicAdd(&sAtt[d], al);
    atomicAdd(&sCnt[s], 1);
    atomicAdd(&sCnt[d], 1);
    int p = atomicAdd(&fill[d], 1);
    eS[p] = s;
    eA[p] = al;
  }
  __syncthreads();

  if (tid < NN) scores[g * NN + tid] = sAtt[tid] / (float)sCnt[tid];

  // aggregation: 4 node groups x 64 threads, float4 over 256 features
  float* outg = out + (size_t)g * NN * DG;
  const int grp = tid >> 6, tf = tid & 63;
  float4 bias = *(const float4*)&b_gat[tf * 4];
  for (int n = grp; n < NN; n += 4) {
    float4 acc = bias;
    const int p1 = offs[n + 1];
    for (int p = offs[n]; p < p1; p++) {
      float al = eA[p];
      float4 hv = *(const float4*)&h2g[(size_t)eS[p] * DG + tf * 4];
      acc.x = fmaf(hv.x, al, acc.x);
      acc.y = fmaf(hv.y, al, acc.y);
      acc.z = fmaf(hv.z, al, acc.z);
      acc.w = fmaf(hv.w, al, acc.w);
    }
    *(float4*)&outg[(size_t)n * DG + tf * 4] = acc;
  }
}

// ---------------------------------------------------------------------------
// Radix-select top-50 of 25600 scores (single block, 1024 threads).
// 4 passes of 8-bit MSB histograms -> exact 50th-largest key, then collect
// (>thr) candidates + (==thr) smallest indices, single-wave sort, write order
// matching jax.lax.top_k (desc score, ties by ascending index).
// ---------------------------------------------------------------------------
__global__ __launch_bounds__(1024) void topk_radix(
    const float* __restrict__ scores, int* __restrict__ topk) {
  const int tid = threadIdx.x;
  unsigned key[25];
#pragma unroll
  for (int u = 0; u < 25; u++) key[u] = fmap(scores[tid + u * 1024]);

  __shared__ unsigned hist[16][256];
  __shared__ unsigned total[256];
  __shared__ unsigned sPref;
  __shared__ int sNeed;
  const int wv = tid >> 6;
  unsigned pref = 0;
  int plen = 0, need = KTOP;
  for (int pass = 0; pass < 4; pass++) {
    const int shift = 24 - 8 * pass;
    for (int i = tid; i < 16 * 256; i += 1024) ((unsigned*)hist)[i] = 0;
    __syncthreads();
#pragma unroll
    for (int u = 0; u < 25; u++) {
      unsigned k = key[u];
      bool ok = (plen == 0) || ((k >> (32 - plen)) == (pref >> (32 - plen)));
      if (ok) atomicAdd(&hist[wv][(k >> shift) & 255], 1u);
    }
    __syncthreads();
    if (tid < 256) {
      unsigned s = 0;
      for (int w = 0; w < 16; w++) s += hist[w][tid];
      total[tid] = s;
    }
    __syncthreads();
    if (tid == 0) {
      unsigned cum = 0;
      int b = 255;
      for (; b > 0; b--) {
        cum += total[b];
        if ((int)cum >= need) break;
      }
      if ((int)cum < need) cum += total[0];  // b==0 fallthrough
      sPref = pref | ((unsigned)b << shift);
      sNeed = need - (int)(cum - total[b]);
    }
    __syncthreads();
    pref = sPref;
    need = sNeed;
    plen += 8;
    __syncthreads();
  }

  const unsigned thr = pref;
  __shared__ int nGt;
  __shared__ unsigned long long cand[64];
  __shared__ int eqMin;
  if (tid == 0) nGt = 0;
  __syncthreads();
  unsigned eqmask = 0;
#pragma unroll
  for (int u = 0; u < 25; u++) {
    unsigned k = key[u];
    if (k > thr) {
      int p = atomicAdd(&nGt, 1);
      cand[p] = ((unsigned long long)k << 32) | (unsigned)(~(tid + u * 1024));
    } else if (k == thr) {
      eqmask |= 1u << u;
    }
  }
  __syncthreads();
  const int base = nGt;  // = KTOP - need
  for (int r = 0; r < need; r++) {
    if (tid == 0) eqMin = 0x7fffffff;
    __syncthreads();
    int mymin = 0x7fffffff;
    unsigned mm = eqmask;
    while (mm) {
      int u = __ffs(mm) - 1;
      mm &= mm - 1;
      int idx = tid + u * 1024;
      if (idx < mymin) mymin = idx;
    }
#pragma unroll
    for (int o = 32; o; o >>= 1) {
      int ot = __shfl_down(mymin, o);
      if (ot < mymin) mymin = ot;
    }
    if ((tid & 63) == 0 && mymin != 0x7fffffff) atomicMin(&eqMin, mymin);
    __syncthreads();
    int sel = eqMin;
    if (tid == 0) topk[base + r] = sel;
    if ((sel & 1023) == tid) eqmask &= ~(1u << (sel >> 10));
    __syncthreads();
  }
  if (tid < 64) {
    unsigned long long c = (tid < base) ? cand[tid] : 0ull;
    for (int r = 0; r < base; r++) {
      unsigned long long m = c;
#pragma unroll
      for (int o = 32; o; o >>= 1) {
        unsigned long long t2 = __shfl_down(m, o);
        if (t2 > m) m = t2;
      }
      m = __shfl(m, 0);
      if (tid == 0) topk[r] = (int)(~(unsigned)m);
      if (c == m) c = 0ull;
    }
  }
}

// ---------------------------------------------------------------------------
// Project the 50 selected rows: out[i,:] = gnn[idx[i],:] @ W_proj + b_proj
// ---------------------------------------------------------------------------
__global__ __launch_bounds__(256) void proj_kernel(
    const float* __restrict__ gnn, const int* __restrict__ topk,
    const float* __restrict__ Wp, const float* __restrict__ bp,
    float* __restrict__ outp) {
  const int bi = blockIdx.x >> 2;
  const int c0 = (blockIdx.x & 3) * 256;
  const int tid = threadIdx.x;
  __shared__ float row[DG];
  const int node = topk[bi];
  row[tid] = gnn[(size_t)node * DG + tid];
  __syncthreads();
  float acc = 0.f;
  for (int k = 0; k < DG; k++)
    acc = fmaf(row[k], Wp[(size_t)k * PO + c0 + tid], acc);
  outp[(size_t)bi * PO + c0 + tid] = acc + bp[c0 + tid];
}

// ---------------------------------------------------------------------------
extern "C" void kernel_launch(void* const* d_in, const int* in_sizes, int n_in,
                              void* d_out, int out_size, void* d_ws,
                              size_t ws_size, hipStream_t stream) {
  const float* x      = (const float*)d_in[0];
  const int*   ei     = (const int*)d_in[1];
  const float* W_gcn  = (const float*)d_in[2];
  const float* b_gcn  = (const float*)d_in[3];
  const float* W_gat  = (const float*)d_in[4];
  const float* b_gat  = (const float*)d_in[5];
  const float* a_src  = (const float*)d_in[6];
  const float* a_dst  = (const float*)d_in[7];
  const float* W_proj = (const float*)d_in[8];
  const float* b_proj = (const float*)d_in[9];
  float* outp = (float*)d_out;

  // workspace (~110 MB):
  //  [0 .. 52.4M)    h0 f32 [25600][512]; later reused: h2 [25600][256] at 0,
  //                  gnn [25600][256] at +26.2M (h0 dead after gcn_agg)
  //  [52.4M ..104.9M) h1 f32 [25600][512]
  //  [104.9M .. )    WgcnT hi/lo, WgatT hi/lo, scores, topk
  char* ws = (char*)d_ws;
  float*  h0       = (float*)ws;
  float*  h2       = (float*)ws;
  float*  gnn      = (float*)(ws + 26214400);
  float*  h1       = (float*)(ws + 52428800);
  char*   wsc      = ws + 104857600;
  ushort* WgcnT_hi = (ushort*)(wsc);
  ushort* WgcnT_lo = (ushort*)(wsc + 2097152);
  ushort* WgatT_hi = (ushort*)(wsc + 4194304);
  ushort* WgatT_lo = (ushort*)(wsc + 4456448);
  float*  scores   = (float*)(wsc + 4718592);
  int*    topk     = (int*)(wsc + 4820992);

  const int M = NB * NN;  // 25600

  tsplit<11><<<(HG * FIN + 255) / 256, 256, 0, stream>>>(W_gcn, WgcnT_hi,
                                                         WgcnT_lo, HG);
  tsplit<9><<<(DG * HG + 255) / 256, 256, 0, stream>>>(W_gat, WgatT_hi,
                                                       WgatT_lo, DG);
  // H0 = x @ W_gcn   [25600,2048]x[2048,512]
  gemm_split_mfma<256, 11><<<dim3(HG / 256, M / 128), 256, 0, stream>>>(
      x, WgcnT_hi, WgcnT_lo, h0, M, HG);
  // H1 = relu(norm-agg(H0) + b_gcn)
  gcn_agg<<<NB, 512, 0, stream>>>(h0, ei, b_gcn, h1);
  // H2 = H1 @ W_gat  [25600,512]x[512,256]
  gemm_split_mfma<128, 9><<<dim3(DG / 128, M / 128), 256, 0, stream>>>(
      h1, WgatT_hi, WgatT_lo, h2, M, DG);
  // GAT attention + aggregation + patch scores
  gat_kernel<<<NB, 256, 0, stream>>>(h2, ei, a_src, a_dst, b_gat, gnn, scores);
  // top-50
  topk_radix<<<1, 1024, 0, stream>>>(scores, topk);
  // project selected rows
  proj_kernel<<<KTOP * 4, 256, 0, stream>>>(gnn, topk, W_proj, b_proj, outp);
}